// Round 1
// baseline (2398.568 us; speedup 1.0000x reference)
//
#include <hip/hip_runtime.h>
#include <hip/hip_bf16.h>
#include <hip/hip_fp16.h>

#define NB 8
#define NP 8192
#define NC 64
#define NM 2048
#define NK 32
#define RAD2 0.04f

typedef unsigned int u32;
typedef unsigned long long u64;
typedef _Float16 f16x8 __attribute__((ext_vector_type(8)));
typedef float f32x4 __attribute__((ext_vector_type(4)));

// exact reference arithmetic: ((dx*dx + dy*dy) + dz*dz), no FMA contraction
__device__ __forceinline__ float d2e(float ax, float ay, float az,
                                     float bx, float by, float bz) {
    float dx = __fsub_rn(ax, bx), dy = __fsub_rn(ay, by), dz = __fsub_rn(az, bz);
    return __fadd_rn(__fadd_rn(__fmul_rn(dx, dx), __fmul_rn(dy, dy)), __fmul_rn(dz, dz));
}

// ---------------- Kernel 1: farthest point sampling (1 block per cloud) ----
__global__ __launch_bounds__(256, 1) void fps_kernel(const float* __restrict__ pos,
                                                     float* __restrict__ pos_s) {
    __shared__ float spos[NP * 3];
    __shared__ u64 red[2][4];
    const int b = blockIdx.x;
    const int tid = threadIdx.x;
    const float* pb = pos + (size_t)b * (NP * 3);
    for (int i = tid; i < NP * 3; i += 256) spos[i] = pb[i];
    __syncthreads();

    float px[32], py[32], pz[32], mind[32];
    const float s0x = spos[0], s0y = spos[1], s0z = spos[2];
    float bv = -1.0f; int bp = 0;
#pragma unroll
    for (int i = 0; i < 32; ++i) {
        int p = tid + (i << 8);
        px[i] = spos[3 * p]; py[i] = spos[3 * p + 1]; pz[i] = spos[3 * p + 2];
        float d = d2e(px[i], py[i], pz[i], s0x, s0y, s0z);
        mind[i] = d;
        if (d > bv) { bv = d; bp = p; }   // ascending p => first-max tie-break
    }
    float* outp = pos_s + (size_t)b * (NM * 3);
    if (tid == 0) { outp[0] = s0x; outp[1] = s0y; outp[2] = s0z; }
    const int lane = tid & 63, wid = tid >> 6;

    for (int t = 1; t < NM; ++t) {
        // pack: max value, tie -> min index
        u64 key = ((u64)__float_as_uint(bv) << 32) | (u32)(0xFFFFFFFFu - (u32)bp);
#pragma unroll
        for (int off = 32; off > 0; off >>= 1) {
            u64 o = __shfl_xor(key, off);
            if (o > key) key = o;
        }
        if (lane == 0) red[t & 1][wid] = key;
        __syncthreads();
        u64 k0 = red[t & 1][0], k1 = red[t & 1][1];
        u64 k2 = red[t & 1][2], k3 = red[t & 1][3];
        if (k1 > k0) k0 = k1;
        if (k3 > k2) k2 = k3;
        if (k2 > k0) k0 = k2;
        const int nxt = (int)(0xFFFFFFFFu - (u32)k0);
        const float sx = spos[3 * nxt], sy = spos[3 * nxt + 1], sz = spos[3 * nxt + 2];
        if (tid == 0) { outp[3 * t] = sx; outp[3 * t + 1] = sy; outp[3 * t + 2] = sz; }
        bv = -1.0f; bp = 0;
#pragma unroll
        for (int i = 0; i < 32; ++i) {
            float d = d2e(px[i], py[i], pz[i], sx, sy, sz);
            float nm = fminf(mind[i], d);
            mind[i] = nm;
            if (nm > bv) { bv = nm; bp = tid + (i << 8); }
        }
    }
}

// ---------------- Kernel 2: radius-limited 32-NN (8 queries per block) -----
#define GQ 8
#define CAP 768
__global__ __launch_bounds__(256, 1) void knn_kernel(const float* __restrict__ pos,
                                                     const float* __restrict__ pos_s,
                                                     int* __restrict__ nbr) {
    __shared__ u64 keys[GQ][CAP];
    __shared__ int cnt[GQ];
    const int qbase = blockIdx.x * GQ;
    const int b = qbase >> 11;
    const int tid = threadIdx.x;
    if (tid < GQ) cnt[tid] = 0;
    for (int i = tid; i < GQ * NK; i += 256) nbr[qbase * NK + i] = -1;

    float qx[GQ], qy[GQ], qz[GQ];
#pragma unroll
    for (int q = 0; q < GQ; ++q) {
        qx[q] = pos_s[(qbase + q) * 3];
        qy[q] = pos_s[(qbase + q) * 3 + 1];
        qz[q] = pos_s[(qbase + q) * 3 + 2];
    }
    __syncthreads();

    const float* pb = pos + (size_t)b * (NP * 3);
    for (int i = 0; i < NP / 256; ++i) {
        int p = tid + (i << 8);
        float x = pb[3 * p], y = pb[3 * p + 1], z = pb[3 * p + 2];
#pragma unroll
        for (int q = 0; q < GQ; ++q) {
            float d = d2e(x, y, z, qx[q], qy[q], qz[q]);
            if (d <= RAD2) {
                int slot = atomicAdd(&cnt[q], 1);
                if (slot < CAP) keys[q][slot] = ((u64)__float_as_uint(d) << 32) | (u32)p;
            }
        }
    }
    __syncthreads();

    // exact rank selection: keys are unique (idx in low bits) -> stable top-k
    for (int q = 0; q < GQ; ++q) {
        int c = min(cnt[q], CAP);
        for (int j = tid; j < c; j += 256) {
            u64 key = keys[q][j];
            int rank = 0;
            for (int t2 = 0; t2 < c; ++t2) rank += (keys[q][t2] < key) ? 1 : 0;
            if (rank < NK) nbr[(qbase + q) * NK + rank] = (int)(u32)(key & 0xFFFFFFFFull);
        }
    }
}

// ---------------- Kernel 3: gather + MLP (fp16 MFMA) + masked max-pool -----
#define FPAD 104
#define HPAD 72
#define TG 8
__global__ __launch_bounds__(512, 1) void mlp_kernel(
    const float* __restrict__ x, const float* __restrict__ pos,
    const float* __restrict__ W0, const float* __restrict__ b0,
    const float* __restrict__ W1, const float* __restrict__ b1,
    const float* __restrict__ W2, const float* __restrict__ b2,
    const float* __restrict__ pos_s, const int* __restrict__ nbr,
    float* __restrict__ x1) {
    __shared__ _Float16 feat[256 * FPAD];   // reused as h2[256][HPAD] after GEMM1
    __shared__ _Float16 h1[256 * HPAD];
    __shared__ _Float16 wt0[64 * FPAD];
    __shared__ _Float16 wt1[64 * HPAD];
    __shared__ _Float16 wt2[128 * HPAD];
    __shared__ float bias0[64], bias1[64], bias2[128];
    __shared__ int vld[256];

    const int tid = threadIdx.x;
    const int g0 = blockIdx.x * TG;
    const int b = g0 >> 11;

    // stage weights transposed: wt[c][j] = W[j][c], zero-padded in K
    for (int idx = tid; idx < 64 * FPAD; idx += 512) {
        int c2 = idx / FPAD, j = idx - c2 * FPAD;
        wt0[idx] = (_Float16)((j < 67) ? W0[j * 64 + c2] : 0.0f);
    }
    for (int idx = tid; idx < 64 * HPAD; idx += 512) {
        int c2 = idx / HPAD, j = idx - c2 * HPAD;
        wt1[idx] = (_Float16)((j < 64) ? W1[j * 64 + c2] : 0.0f);
    }
    for (int idx = tid; idx < 128 * HPAD; idx += 512) {
        int c2 = idx / HPAD, j = idx - c2 * HPAD;
        wt2[idx] = (_Float16)((j < 64) ? W2[j * 128 + c2] : 0.0f);
    }
    if (tid < 64) { bias0[tid] = b0[tid]; bias1[tid] = b1[tid]; }
    else if (tid < 192) bias2[tid - 64] = b2[tid - 64];

    // gather features: 2 threads per row, rows = (group, k)
    {
        int r = tid >> 1, half = tid & 1;
        int g = g0 + (r >> 5), k = r & 31;
        int nid = nbr[g * NK + k];
        int nid2 = nid < 0 ? 0 : nid;
        const float* xr = x + ((size_t)b * NP + nid2) * NC + half * 32;
        _Float16* dst = &feat[r * FPAD + half * 32];
#pragma unroll
        for (int i = 0; i < 8; ++i) {
            float4 v = *(const float4*)(xr + i * 4);
            dst[i * 4 + 0] = (_Float16)v.x; dst[i * 4 + 1] = (_Float16)v.y;
            dst[i * 4 + 2] = (_Float16)v.z; dst[i * 4 + 3] = (_Float16)v.w;
        }
        if (half) {
            const float* pj = pos + ((size_t)b * NP + nid2) * 3;
            const float* ps = pos_s + (size_t)g * 3;
            feat[r * FPAD + 64] = (_Float16)(pj[0] - ps[0]);
            feat[r * FPAD + 65] = (_Float16)(pj[1] - ps[1]);
            feat[r * FPAD + 66] = (_Float16)(pj[2] - ps[2]);
#pragma unroll
            for (int j = 67; j < 96; ++j) feat[r * FPAD + j] = (_Float16)0.0f;
        } else {
            vld[r] = (nid >= 0) ? 1 : 0;
        }
    }
    __syncthreads();

    const int lane = tid & 63, w = tid >> 6;
    const int rb = w * 32;          // this wave owns one (b,m) group = 32 rows
    const int ar = lane & 15;
    const int kg = lane >> 4;

    // GEMM1: feat[256x96] x W0 -> h1[256x64], relu
    {
        f32x4 acc[2][4] = {};
#pragma unroll
        for (int kt = 0; kt < 3; ++kt) {
            f16x8 a0 = *(const f16x8*)&feat[(rb + ar) * FPAD + kt * 32 + kg * 8];
            f16x8 a1 = *(const f16x8*)&feat[(rb + 16 + ar) * FPAD + kt * 32 + kg * 8];
#pragma unroll
            for (int nt = 0; nt < 4; ++nt) {
                f16x8 bb = *(const f16x8*)&wt0[(nt * 16 + ar) * FPAD + kt * 32 + kg * 8];
                acc[0][nt] = __builtin_amdgcn_mfma_f32_16x16x32_f16(a0, bb, acc[0][nt], 0, 0, 0);
                acc[1][nt] = __builtin_amdgcn_mfma_f32_16x16x32_f16(a1, bb, acc[1][nt], 0, 0, 0);
            }
        }
#pragma unroll
        for (int mt = 0; mt < 2; ++mt)
#pragma unroll
            for (int nt = 0; nt < 4; ++nt)
#pragma unroll
                for (int ri = 0; ri < 4; ++ri) {
                    int row = rb + mt * 16 + kg * 4 + ri;
                    int col = nt * 16 + ar;
                    float v = fmaxf(acc[mt][nt][ri] + bias0[col], 0.0f);
                    h1[row * HPAD + col] = (_Float16)v;
                }
    }
    __syncthreads();

    // GEMM2: h1[256x64] x W1 -> h2 (reusing feat), relu
    _Float16* h2 = feat;
    {
        f32x4 acc[2][4] = {};
#pragma unroll
        for (int kt = 0; kt < 2; ++kt) {
            f16x8 a0 = *(const f16x8*)&h1[(rb + ar) * HPAD + kt * 32 + kg * 8];
            f16x8 a1 = *(const f16x8*)&h1[(rb + 16 + ar) * HPAD + kt * 32 + kg * 8];
#pragma unroll
            for (int nt = 0; nt < 4; ++nt) {
                f16x8 bb = *(const f16x8*)&wt1[(nt * 16 + ar) * HPAD + kt * 32 + kg * 8];
                acc[0][nt] = __builtin_amdgcn_mfma_f32_16x16x32_f16(a0, bb, acc[0][nt], 0, 0, 0);
                acc[1][nt] = __builtin_amdgcn_mfma_f32_16x16x32_f16(a1, bb, acc[1][nt], 0, 0, 0);
            }
        }
#pragma unroll
        for (int mt = 0; mt < 2; ++mt)
#pragma unroll
            for (int nt = 0; nt < 4; ++nt)
#pragma unroll
                for (int ri = 0; ri < 4; ++ri) {
                    int row = rb + mt * 16 + kg * 4 + ri;
                    int col = nt * 16 + ar;
                    float v = fmaxf(acc[mt][nt][ri] + bias1[col], 0.0f);
                    h2[row * HPAD + col] = (_Float16)v;
                }
    }
    __syncthreads();

    // GEMM3: h2[256x64] x W2 -> [256x128], relu + masked max-pool over k=32
    {
        f32x4 acc[2][8] = {};
#pragma unroll
        for (int kt = 0; kt < 2; ++kt) {
            f16x8 a0 = *(const f16x8*)&h2[(rb + ar) * HPAD + kt * 32 + kg * 8];
            f16x8 a1 = *(const f16x8*)&h2[(rb + 16 + ar) * HPAD + kt * 32 + kg * 8];
#pragma unroll
            for (int nt = 0; nt < 8; ++nt) {
                f16x8 bb = *(const f16x8*)&wt2[(nt * 16 + ar) * HPAD + kt * 32 + kg * 8];
                acc[0][nt] = __builtin_amdgcn_mfma_f32_16x16x32_f16(a0, bb, acc[0][nt], 0, 0, 0);
                acc[1][nt] = __builtin_amdgcn_mfma_f32_16x16x32_f16(a1, bb, acc[1][nt], 0, 0, 0);
            }
        }
        const int g = g0 + w;
#pragma unroll
        for (int nt = 0; nt < 8; ++nt) {
            int col = nt * 16 + ar;
            float bz = bias2[col];
            float bmax = 0.0f;   // h>=0 post-relu and self is always valid
#pragma unroll
            for (int mt = 0; mt < 2; ++mt)
#pragma unroll
                for (int ri = 0; ri < 4; ++ri) {
                    int row = rb + mt * 16 + kg * 4 + ri;
                    float v = fmaxf(acc[mt][nt][ri] + bz, 0.0f);
                    bmax = fmaxf(bmax, vld[row] ? v : 0.0f);
                }
            bmax = fmaxf(bmax, __shfl_xor(bmax, 16));
            bmax = fmaxf(bmax, __shfl_xor(bmax, 32));
            if (lane < 16) x1[(size_t)g * 128 + nt * 16 + lane] = bmax;
        }
    }
}

extern "C" void kernel_launch(void* const* d_in, const int* in_sizes, int n_in,
                              void* d_out, int out_size, void* d_ws, size_t ws_size,
                              hipStream_t stream) {
    const float* x   = (const float*)d_in[0];
    const float* pos = (const float*)d_in[1];
    const float* W0  = (const float*)d_in[2];
    const float* b0  = (const float*)d_in[3];
    const float* W1  = (const float*)d_in[4];
    const float* b1  = (const float*)d_in[5];
    const float* W2  = (const float*)d_in[6];
    const float* b2  = (const float*)d_in[7];
    float* x1    = (float*)d_out;
    float* pos_s = x1 + (size_t)NB * NM * 128;   // outputs concatenated: x1 then pos_s
    int* nbr = (int*)d_ws;                        // [NB*NM, NK] int32 = 2MB

    fps_kernel<<<NB, 256, 0, stream>>>(pos, pos_s);
    knn_kernel<<<(NB * NM) / GQ, 256, 0, stream>>>(pos, pos_s, nbr);
    mlp_kernel<<<(NB * NM) / TG, 512, 0, stream>>>(x, pos, W0, b0, W1, b1, W2, b2,
                                                   pos_s, nbr, x1);
}